// Round 4
// baseline (1557.012 us; speedup 1.0000x reference)
//
#include <hip/hip_runtime.h>

// FusedMoEIntegrator — MI355X/gfx950, round 3.
// Changes vs round 2:
//  - XCD-aware bijective block swizzle in gemm_k (FETCH was 8x ideal).
//  - halt-gate GEMM fused into F1 (shared A): N=2304, split epilogue.
//  - combine_k folded into shared-expert exp2 (exp2sc_k): routed exp2 writes
//    pre-weighted packed pairs; shared exp2 combines + writes x_next/v_next.
//  - F2 epilogue writes bf16(integrated) into ctx x-half (ctx_k only at init).
//  - padPK shrinks to routed-only 64 MB (rh aliases it exactly).

#define TOK   16384
#define DDIM  1024
#define NEXP  8
#define DTC   0.1f
#define MAXDESC 512
#define NDBLK 392
#define SHBASE 33664   // hiddenG row base for shared-expert rows (>= 263*128)

using f32x4 = __attribute__((ext_vector_type(4))) float;
using bfv8  = __attribute__((ext_vector_type(8))) short;

__device__ __forceinline__ unsigned short f2bf(float x){
  unsigned u = __builtin_bit_cast(unsigned, x);
  u += 0x7fffu + ((u >> 16) & 1u);
  return (unsigned short)(u >> 16);
}
__device__ __forceinline__ float bf2f(unsigned short h){
  return __builtin_bit_cast(float, ((unsigned)h) << 16);
}
__device__ __forceinline__ float geluf(float x){
  return 0.5f * x * (1.0f + erff(x * 0.7071067811865476f));
}
__device__ __forceinline__ float sigmf(float x){ return 1.0f/(1.0f+__expf(-x)); }
__device__ __forceinline__ float softpf(float x){
  return fmaxf(x, 0.0f) + __logf(1.0f + __expf(-fabsf(x)));
}
__device__ __forceinline__ f32x4 mfma16(bfv8 a, bfv8 b, f32x4 c){
  return __builtin_amdgcn_mfma_f32_16x16x32_bf16(a, b, c, 0, 0, 0);
}
typedef __attribute__((address_space(1))) const void gvoid_t;
typedef __attribute__((address_space(3))) void svoid_t;
__device__ __forceinline__ void gload16(const void* g, void* l){
  __builtin_amdgcn_global_load_lds((gvoid_t*)g, (svoid_t*)l, 16, 0, 0);
}

// -------- transpose+cast: src f32 [R][C] (batch z) -> dst bf16 [C][R] --------
__global__ __launch_bounds__(256) void transpose_cast(
    const float* __restrict__ src, unsigned short* __restrict__ dst, int R, int C)
{
  __shared__ float tile[32][33];
  size_t bo = (size_t)blockIdx.z * R * C;
  const float* s = src + bo;
  unsigned short* d = dst + bo;
  int c0 = blockIdx.x * 32, r0 = blockIdx.y * 32;
  int tx = threadIdx.x, ty = threadIdx.y;
  #pragma unroll
  for (int j = 0; j < 4; j++)
    tile[ty + 8*j][tx] = s[(size_t)(r0 + ty + 8*j) * C + c0 + tx];
  __syncthreads();
  #pragma unroll
  for (int j = 0; j < 4; j++)
    d[(size_t)(c0 + ty + 8*j) * R + r0 + tx] = f2bf(tile[tx][ty + 8*j]);
}

// -------- ctx init: x-half = bf16(out), v-half = 0 ---------------------------
__global__ __launch_bounds__(256) void ctx_k(
    const float* __restrict__ outf, unsigned short* __restrict__ ctx)
{
  const int n = TOK * 256;
  for (int i = blockIdx.x * 256 + threadIdx.x; i < n; i += gridDim.x * 256) {
    int t = i >> 8, c4 = (i & 255) * 4;
    float4 xi = ((const float4*)outf)[i];
    ushort4 xb = {f2bf(xi.x), f2bf(xi.y), f2bf(xi.z), f2bf(xi.w)};
    *(ushort4*)&ctx[(size_t)t*2048 + c4] = xb;
    *(ushort4*)&ctx[(size_t)t*2048 + 1024 + c4] = ushort4{0,0,0,0};
  }
}

// -------- main GEMM: C[M,N] = A[M,K](bf16,lda) @ BT[N,K]^T -------------------
// 128x128 tile, BK=64, global_load_lds + XOR swizzle, XCD-aware block swizzle.
// EPI 0: obf[row*N+col] = bf16(gelu(acc+bias[col]))              (router h1)
// EPI 2: col<2048 -> obf=rh (gelu, b=bias); else obf2=h1 (gelu, b=bias2)
// EPI 1: nv = integ + halt[row]*(acc+bias)*iw[col]; integ=nv; ctxX=bf16(nv)
template<int EPI>
__global__ __launch_bounds__(256) void gemm_k(
    const unsigned short* __restrict__ A, int lda,
    const unsigned short* __restrict__ BT,
    const float* __restrict__ bias, const float* __restrict__ bias2,
    int Kd, int N,
    unsigned short* __restrict__ obf, unsigned short* __restrict__ obf2,
    const float* __restrict__ halt, const float* __restrict__ iw,
    float* __restrict__ integ, unsigned short* __restrict__ ctxX)
{
  __shared__ unsigned short As[128][64];
  __shared__ unsigned short Bs[128][64];
  // XCD-aware bijective swizzle (grid total must be %8==0; all ours are)
  const int total = gridDim.x * gridDim.y;
  const int bid = blockIdx.y * gridDim.x + blockIdx.x;
  const int swz = (bid & 7) * (total >> 3) + (bid >> 3);
  const int bx = swz % gridDim.x, by = swz / gridDim.x;

  const int tid  = threadIdx.x, lane = tid & 63, w = tid >> 6;
  const int wm   = w >> 1, wn = w & 1;
  const int gm0  = by * 128, gn0 = bx * 128;
  const int r8   = lane >> 3;
  const int sseg = (lane & 7) ^ r8;

  const unsigned short* aga[4];
  const unsigned short* bga[4];
  #pragma unroll
  for (int c = 0; c < 4; c++) {
    aga[c] = A  + (size_t)(gm0 + w*32 + c*8 + r8) * lda + sseg*8;
    bga[c] = BT + (size_t)(gn0 + w*32 + c*8 + r8) * Kd  + sseg*8;
  }

  f32x4 acc[4][4];
  #pragma unroll
  for (int i = 0; i < 4; i++)
    #pragma unroll
    for (int j = 0; j < 4; j++)
      acc[i][j] = f32x4{0.f,0.f,0.f,0.f};

  const int xr = (lane & 7) << 3;
  for (int k0 = 0; k0 < Kd; k0 += 64) {
    #pragma unroll
    for (int c = 0; c < 4; c++) gload16(aga[c] + k0, &As[w*32 + c*8][0]);
    #pragma unroll
    for (int c = 0; c < 4; c++) gload16(bga[c] + k0, &Bs[w*32 + c*8][0]);
    __syncthreads();
    #pragma unroll
    for (int kk = 0; kk < 64; kk += 32) {
      const int kof = kk + ((lane >> 4) << 3);
      bfv8 a[4], b[4];
      #pragma unroll
      for (int mf = 0; mf < 4; mf++)
        a[mf] = *(const bfv8*)&As[wm*64 + mf*16 + (lane & 15)][kof ^ xr];
      #pragma unroll
      for (int nf = 0; nf < 4; nf++)
        b[nf] = *(const bfv8*)&Bs[wn*64 + nf*16 + (lane & 15)][kof ^ xr];
      #pragma unroll
      for (int mf = 0; mf < 4; mf++)
        #pragma unroll
        for (int nf = 0; nf < 4; nf++)
          acc[mf][nf] = mfma16(a[mf], b[nf], acc[mf][nf]);
    }
    __syncthreads();
  }

  #pragma unroll
  for (int mf = 0; mf < 4; mf++) {
    #pragma unroll
    for (int nf = 0; nf < 4; nf++) {
      int col = gn0 + wn*64 + nf*16 + (lane & 15);
      float bc;
      if (EPI == 2) bc = (col < 2048) ? bias[col] : bias2[col - 2048];
      else          bc = bias[col];
      #pragma unroll
      for (int r = 0; r < 4; r++) {
        int row = gm0 + wm*64 + mf*16 + ((lane >> 4) << 2) + r;
        float v = acc[mf][nf][r] + bc;
        if (EPI == 0) {
          obf[(size_t)row * N + col] = f2bf(geluf(v));
        } else if (EPI == 2) {
          if (col < 2048) obf [(size_t)row * 2048 + col]        = f2bf(geluf(v));
          else            obf2[(size_t)row * 256 + (col - 2048)] = f2bf(geluf(v));
        } else {
          size_t ix = (size_t)row * DDIM + col;
          float nv = integ[ix] + halt[row] * v * iw[col];
          integ[ix] = nv;
          ctxX[(size_t)row * 2048 + col] = f2bf(nv);
        }
      }
    }
  }
}

// -------- router second stage ------------------------------------------------
__global__ __launch_bounds__(256) void router_k(
    const unsigned short* __restrict__ h1, const float* __restrict__ w_r2,
    const float* __restrict__ b_r2, int* __restrict__ topi, float* __restrict__ topw)
{
  int t = blockIdx.x * 4 + (threadIdx.x >> 6);
  int lane = threadIdx.x & 63;
  const unsigned short* hp = h1 + (size_t)t * 256 + lane * 4;
  float hv[4];
  #pragma unroll
  for (int j = 0; j < 4; j++) hv[j] = bf2f(hp[j]);
  float acc[8];
  #pragma unroll
  for (int e = 0; e < 8; e++) acc[e] = 0.f;
  #pragma unroll
  for (int j = 0; j < 4; j++) {
    const float* wr = w_r2 + (size_t)(lane*4 + j) * 8;
    #pragma unroll
    for (int e = 0; e < 8; e++) acc[e] += hv[j] * wr[e];
  }
  #pragma unroll
  for (int off = 32; off > 0; off >>= 1)
    #pragma unroll
    for (int e = 0; e < 8; e++) acc[e] += __shfl_xor(acc[e], off);
  if (lane == 0) {
    float lg[8];
    #pragma unroll
    for (int e = 0; e < 8; e++) lg[e] = acc[e] + b_r2[e];
    int i0 = 0; float m0 = lg[0];
    #pragma unroll
    for (int e = 1; e < 8; e++) if (lg[e] > m0) { m0 = lg[e]; i0 = e; }
    int i1 = -1; float m1 = -3.4e38f;
    #pragma unroll
    for (int e = 0; e < 8; e++) if (e != i0 && lg[e] > m1) { m1 = lg[e]; i1 = e; }
    float w0 = 1.0f / (1.0f + expf(m1 - m0));
    topi[t*2] = i0; topi[t*2+1] = i1;
    topw[t*2] = w0; topw[t*2+1] = 1.0f - w0;
  }
}

// -------- halt gate second stage ---------------------------------------------
__global__ __launch_bounds__(256) void haltgate_k(
    const unsigned short* __restrict__ h1, const float* __restrict__ w_h2,
    const float* __restrict__ b_h2, float* __restrict__ halt)
{
  int t = blockIdx.x * 4 + (threadIdx.x >> 6);
  int lane = threadIdx.x & 63;
  const unsigned short* hp = h1 + (size_t)t * 256 + lane * 4;
  float s = 0.f;
  #pragma unroll
  for (int j = 0; j < 4; j++) s += bf2f(hp[j]) * w_h2[lane*4 + j];
  #pragma unroll
  for (int off = 32; off > 0; off >>= 1) s += __shfl_xor(s, off);
  if (lane == 0) halt[t] = sigmf(s + b_h2[0]);
}

// -------- expert bucketing ---------------------------------------------------
__global__ __launch_bounds__(256) void bucket_k(
    const int* __restrict__ topi, int* __restrict__ cnt, int* __restrict__ slots)
{
  int g = blockIdx.x * 256 + threadIdx.x;
  int e = topi[g];
  int p = atomicAdd(&cnt[e], 1);
  slots[e * 32768 + p] = g;
}

// desc: routed tiles get running hbase; shared (e==8) tiles get SHBASE + o.
__global__ void desc_k(const int* __restrict__ cnt, int4* __restrict__ desc,
                       int* __restrict__ ndesc)
{
  if (threadIdx.x == 0 && blockIdx.x == 0) {
    int nt = 0, hb = 0;
    for (int e = 0; e < NEXP; e++) {
      int c = cnt[e];
      for (int o = 0; o < c; o += 128) {
        int rem = c - o; if (rem > 128) rem = 128;
        desc[nt] = make_int4(e, o, rem, hb);
        nt++; hb += 128;
      }
    }
    for (int o = 0; o < TOK; o += 128) {
      desc[nt] = make_int4(8, o, 128, SHBASE + o);
      nt++;
    }
    ndesc[0] = nt;
  }
}

// -------- exp1: hidden[row][64] = gelu(ctx_row @ w1 + b1) (shared + routed) --
__global__ __launch_bounds__(256) void exp1_k(
    const unsigned short* __restrict__ ctx,
    const int4* __restrict__ desc, const int* __restrict__ ndesc,
    const int* __restrict__ slots,
    const unsigned short* __restrict__ ew1T, const float* __restrict__ eb1,
    const unsigned short* __restrict__ ws1T, const float* __restrict__ bs1,
    unsigned short* __restrict__ hiddenG)
{
  __shared__ unsigned short As[128][64];
  __shared__ unsigned short Bs[64][64];
  __shared__ int s_tok[128];
  if (blockIdx.x >= ndesc[0]) return;
  int4 dd = desc[blockIdx.x];
  const int e = dd.x, goff = dd.y, cnt = dd.z, hbase = dd.w;
  const unsigned short* w1 = (e < 8) ? ew1T + (size_t)e * 64 * 2048 : ws1T;
  const float* b1 = (e < 8) ? eb1 + e * 64 : bs1;
  const int tid = threadIdx.x, lane = tid & 63, w = tid >> 6;

  if (tid < 128) {
    int tok;
    if (e < 8) tok = (tid < cnt) ? (slots[e * 32768 + goff + tid] >> 1) : 0;
    else       tok = goff + tid;
    s_tok[tid] = tok;
  }
  __syncthreads();

  const int arow = w*8 + (lane >> 3);
  const int sseg = (lane & 7) ^ (lane >> 3);
  const unsigned short* asrc[4];
  #pragma unroll
  for (int q = 0; q < 4; q++)
    asrc[q] = ctx + (size_t)s_tok[q*32 + arow] * 2048 + sseg * 8;
  const unsigned short* bsrc[2];
  #pragma unroll
  for (int q = 0; q < 2; q++)
    bsrc[q] = w1 + (size_t)(q*32 + arow) * 2048 + sseg * 8;

  f32x4 acc[2][4];
  #pragma unroll
  for (int i = 0; i < 2; i++)
    #pragma unroll
    for (int j = 0; j < 4; j++)
      acc[i][j] = f32x4{0.f,0.f,0.f,0.f};

  const int xr = (lane & 7) << 3;
  for (int k0 = 0; k0 < 2048; k0 += 64) {
    #pragma unroll
    for (int q = 0; q < 4; q++) gload16(asrc[q] + k0, &As[q*32 + w*8][0]);
    #pragma unroll
    for (int q = 0; q < 2; q++) gload16(bsrc[q] + k0, &Bs[q*32 + w*8][0]);
    __syncthreads();
    #pragma unroll
    for (int kk = 0; kk < 64; kk += 32) {
      const int kof = kk + ((lane >> 4) << 3);
      bfv8 a[2], b[4];
      #pragma unroll
      for (int mf = 0; mf < 2; mf++)
        a[mf] = *(const bfv8*)&As[w*32 + mf*16 + (lane & 15)][kof ^ xr];
      #pragma unroll
      for (int nf = 0; nf < 4; nf++)
        b[nf] = *(const bfv8*)&Bs[nf*16 + (lane & 15)][kof ^ xr];
      #pragma unroll
      for (int mf = 0; mf < 2; mf++)
        #pragma unroll
        for (int nf = 0; nf < 4; nf++)
          acc[mf][nf] = mfma16(a[mf], b[nf], acc[mf][nf]);
    }
    __syncthreads();
  }

  #pragma unroll
  for (int mf = 0; mf < 2; mf++) {
    #pragma unroll
    for (int nf = 0; nf < 4; nf++) {
      int col = nf*16 + (lane & 15);
      float bb = b1[col];
      #pragma unroll
      for (int r = 0; r < 4; r++) {
        int row = w*32 + mf*16 + ((lane >> 4) << 2) + r;
        hiddenG[(size_t)(hbase + row) * 64 + col] = f2bf(geluf(acc[mf][nf][r] + bb));
      }
    }
  }
}

// -------- exp2 routed: packed (bf16 cw*v_n | bf16 cw*g*v_n) per slot*d --------
__global__ __launch_bounds__(256) void exp2r_k(
    const unsigned short* __restrict__ hiddenG,
    const int4* __restrict__ desc, const int* __restrict__ ndesc,
    const int* __restrict__ slots, const float* __restrict__ topw,
    const unsigned short* __restrict__ ew2T, const float* __restrict__ eb2,
    const float* __restrict__ swp, const float* __restrict__ mu,
    const unsigned short* __restrict__ ctx,
    unsigned* __restrict__ padPK, int dhalf)
{
  __shared__ unsigned short Hs[128][64];
  __shared__ unsigned short W2s[192][64];
  __shared__ int   s_tok[128];
  __shared__ int   s_sid[128];
  __shared__ float s_cw[128];
  if (blockIdx.x >= ndesc[0]) return;
  int4 dd = desc[blockIdx.x];
  const int e = dd.x, goff = dd.y, cnt = dd.z, hbase = dd.w;
  if (e >= 8) return;   // shared handled by exp2sc_k
  const unsigned short* w2 = ew2T + (size_t)e * 3072 * 64;
  const float* b2 = eb2 + e * 3072;
  const int tid = threadIdx.x, lane = tid & 63, w = tid >> 6;
  const float sw = sigmf(swp[0]);

  if (tid < 128) {
    int tok = 0, sid = 0; float cw = 0.f;
    if (tid < cnt) { int s = slots[e*32768 + goff + tid]; tok = s >> 1; sid = s; cw = (1.f - sw) * topw[s]; }
    s_tok[tid] = tok; s_sid[tid] = sid; s_cw[tid] = cw;
  }
  const int arow = w*8 + (lane >> 3);
  const int sseg = (lane & 7) ^ (lane >> 3);
  #pragma unroll
  for (int q = 0; q < 4; q++)
    gload16(hiddenG + (size_t)(hbase + q*32 + arow) * 64 + sseg*8, &Hs[q*32 + w*8][0]);
  __syncthreads();

  const int xr = (lane & 7) << 3;
  bfv8 afr[2][2];
  #pragma unroll
  for (int mf = 0; mf < 2; mf++)
    #pragma unroll
    for (int kk = 0; kk < 2; kk++) {
      int r = w*32 + mf*16 + (lane & 15);
      int kof = kk*32 + ((lane >> 4) << 3);
      afr[mf][kk] = *(const bfv8*)&Hs[r][kof ^ xr];
    }

  for (int dc = 0; dc < 8; dc++) {
    const int d00 = dhalf * 512 + dc * 64;
    #pragma unroll
    for (int q = 0; q < 6; q++) {
      int row  = q*32 + arow;
      int grow = (row >> 6) * 1024 + d00 + (row & 63);
      gload16(w2 + (size_t)grow * 64 + sseg*8, &W2s[q*32 + w*8][0]);
    }
    __syncthreads();

    f32x4 acc[2][12];
    #pragma unroll
    for (int i = 0; i < 2; i++)
      #pragma unroll
      for (int j = 0; j < 12; j++)
        acc[i][j] = f32x4{0.f,0.f,0.f,0.f};
    #pragma unroll
    for (int kk = 0; kk < 2; kk++) {
      const int kof = kk*32 + ((lane >> 4) << 3);
      #pragma unroll
      for (int nf = 0; nf < 12; nf++) {
        bfv8 b = *(const bfv8*)&W2s[nf*16 + (lane & 15)][kof ^ xr];
        acc[0][nf] = mfma16(afr[0][kk], b, acc[0][nf]);
        acc[1][nf] = mfma16(afr[1][kk], b, acc[1][nf]);
      }
    }

    #pragma unroll
    for (int mf = 0; mf < 2; mf++) {
      #pragma unroll
      for (int cf = 0; cf < 4; cf++) {
        int d = d00 + cf*16 + (lane & 15);
        float ba = b2[d], bb = b2[1024 + d], bg = b2[2048 + d];
        float muv = mu[d];
        #pragma unroll
        for (int r = 0; r < 4; r++) {
          int row = w*32 + mf*16 + ((lane >> 4) << 2) + r;
          if (row >= cnt) continue;
          float cw = s_cw[row]; int tok = s_tok[row];
          float al = sigmf(acc[mf][cf][r] + ba);
          float be = softpf(acc[mf][4 + cf][r] + bb);
          float ga = sigmf(acc[mf][8 + cf][r] + bg);
          float xx = bf2f(ctx[(size_t)tok*2048 + d]);
          float vv = bf2f(ctx[(size_t)tok*2048 + 1024 + d]);
          float vn = al * vv - be * (xx - muv);
          unsigned pk = (unsigned)f2bf(cw * vn) | ((unsigned)f2bf(cw * ga * vn) << 16);
          padPK[(size_t)s_sid[row] * 512 + (d - dhalf*512)] = pk;
        }
      }
    }
    __syncthreads();
  }
}

// -------- exp2 shared + combine: x_next/v_next per token ----------------------
__global__ __launch_bounds__(256) void exp2sc_k(
    const unsigned short* __restrict__ hiddenG,
    const unsigned short* __restrict__ ws2T, const float* __restrict__ bs2,
    const float* __restrict__ swp, const float* __restrict__ mu,
    unsigned short* __restrict__ ctx,
    const unsigned* __restrict__ padPK,
    unsigned short* __restrict__ xaccB, int dhalf)
{
  __shared__ unsigned short Hs[128][64];
  __shared__ unsigned short W2s[192][64];
  const int tid = threadIdx.x, lane = tid & 63, w = tid >> 6;
  const int tbase = blockIdx.x * 128;
  const float sw = sigmf(swp[0]);

  const int arow = w*8 + (lane >> 3);
  const int sseg = (lane & 7) ^ (lane >> 3);
  #pragma unroll
  for (int q = 0; q < 4; q++)
    gload16(hiddenG + (size_t)(SHBASE + tbase + q*32 + arow) * 64 + sseg*8,
            &Hs[q*32 + w*8][0]);
  __syncthreads();

  const int xr = (lane & 7) << 3;
  bfv8 afr[2][2];
  #pragma unroll
  for (int mf = 0; mf < 2; mf++)
    #pragma unroll
    for (int kk = 0; kk < 2; kk++) {
      int r = w*32 + mf*16 + (lane & 15);
      int kof = kk*32 + ((lane >> 4) << 3);
      afr[mf][kk] = *(const bfv8*)&Hs[r][kof ^ xr];
    }

  for (int dc = 0; dc < 8; dc++) {
    const int d00 = dhalf * 512 + dc * 64;
    #pragma unroll
    for (int q = 0; q < 6; q++) {
      int row  = q*32 + arow;
      int grow = (row >> 6) * 1024 + d00 + (row & 63);
      gload16(ws2T + (size_t)grow * 64 + sseg*8, &W2s[q*32 + w*8][0]);
    }
    __syncthreads();

    f32x4 acc[2][12];
    #pragma unroll
    for (int i = 0; i < 2; i++)
      #pragma unroll
      for (int j = 0; j < 12; j++)
        acc[i][j] = f32x4{0.f,0.f,0.f,0.f};
    #pragma unroll
    for (int kk = 0; kk < 2; kk++) {
      const int kof = kk*32 + ((lane >> 4) << 3);
      #pragma unroll
      for (int nf = 0; nf < 12; nf++) {
        bfv8 b = *(const bfv8*)&W2s[nf*16 + (lane & 15)][kof ^ xr];
        acc[0][nf] = mfma16(afr[0][kk], b, acc[0][nf]);
        acc[1][nf] = mfma16(afr[1][kk], b, acc[1][nf]);
      }
    }

    #pragma unroll
    for (int mf = 0; mf < 2; mf++) {
      #pragma unroll
      for (int cf = 0; cf < 4; cf++) {
        int d = d00 + cf*16 + (lane & 15);
        int dl = d - dhalf*512;
        float ba = bs2[d], bb = bs2[1024 + d], bg = bs2[2048 + d];
        float muv = mu[d];
        #pragma unroll
        for (int r = 0; r < 4; r++) {
          int row = w*32 + mf*16 + ((lane >> 4) << 2) + r;
          int tok = tbase + row;
          float al = sigmf(acc[mf][cf][r] + ba);
          float be = softpf(acc[mf][4 + cf][r] + bb);
          float ga = sigmf(acc[mf][8 + cf][r] + bg);
          float xx = bf2f(ctx[(size_t)tok*2048 + d]);
          float vv = bf2f(ctx[(size_t)tok*2048 + 1024 + d]);
          float vn = al * vv - be * (xx - muv);
          unsigned pk0 = padPK[(size_t)(2*tok)     * 512 + dl];
          unsigned pk1 = padPK[(size_t)(2*tok + 1) * 512 + dl];
          float vtot  = sw * vn      + bf2f((unsigned short)(pk0 & 0xffff))
                                     + bf2f((unsigned short)(pk1 & 0xffff));
          float gvtot = sw * ga * vn + bf2f((unsigned short)(pk0 >> 16))
                                     + bf2f((unsigned short)(pk1 >> 16));
          xaccB[(size_t)tok*1024 + d]        = f2bf(xx + DTC * gvtot);
          ctx[(size_t)tok*2048 + 1024 + d]   = f2bf(vtot);
        }
      }
    }
    __syncthreads();
  }
}

// -----------------------------------------------------------------------------
extern "C" void kernel_launch(void* const* d_in, const int* in_sizes, int n_in,
                              void* d_out, int out_size, void* d_ws, size_t ws_size,
                              hipStream_t stream)
{
  const float* x    = (const float*)d_in[0];
  const float* w_r1 = (const float*)d_in[1];
  const float* b_r1 = (const float*)d_in[2];
  const float* w_r2 = (const float*)d_in[3];
  const float* b_r2 = (const float*)d_in[4];
  const float* w_h1 = (const float*)d_in[5];
  const float* b_h1 = (const float*)d_in[6];
  const float* w_h2 = (const float*)d_in[7];
  const float* b_h2 = (const float*)d_in[8];
  const float* ew1  = (const float*)d_in[9];
  const float* eb1  = (const float*)d_in[10];
  const float* ew2  = (const float*)d_in[11];
  const float* eb2  = (const float*)d_in[12];
  const float* w_s1 = (const float*)d_in[13];
  const float* b_s1 = (const float*)d_in[14];
  const float* w_s2 = (const float*)d_in[15];
  const float* b_s2 = (const float*)d_in[16];
  const float* swt  = (const float*)d_in[17];
  const float* w_f1 = (const float*)d_in[18];
  const float* b_f1 = (const float*)d_in[19];
  const float* w_f2 = (const float*)d_in[20];
  const float* b_f2 = (const float*)d_in[21];
  const float* iw   = (const float*)d_in[22];
  const float* mu   = (const float*)d_in[23];
  float* out = (float*)d_out;        // doubles as `integrated`

  char* ws = (char*)d_ws;
  size_t off = 0;
  auto take = [&](size_t bytes) -> char* {
    char* p = ws + off;
    off = (off + bytes + 255) & ~(size_t)255;
    return p;
  };
  const size_t TD4 = (size_t)TOK * DDIM * 4;
  unsigned short* xaccB = (unsigned short*)take((size_t)TOK * 1024 * 2);
  unsigned short* ctx   = (unsigned short*)take((size_t)TOK * 2048 * 2);
  unsigned* padPK = (unsigned*)take((size_t)32768 * 512 * 4);   // 64 MB; rh aliases
  unsigned short* rh = (unsigned short*)padPK;                  // [T][2048] bf16
  unsigned short* hiddenG = (unsigned short*)take((size_t)(SHBASE + TOK) * 64 * 2);
  unsigned short* h1 = (unsigned short*)take((size_t)TOK * 256 * 2);
  float* halt = (float*)take((size_t)TOK * 4);
  int*   topi = (int*)take((size_t)TOK * 2 * 4);
  float* topw = (float*)take((size_t)TOK * 2 * 4);
  int*   cnt  = (int*)take(64);
  int*   ndsc = (int*)take(64);
  int4*  desc = (int4*)take((size_t)MAXDESC * 16);
  int*   slots= (int*)take((size_t)NEXP * 32768 * 4);
  unsigned short* w_r1T = (unsigned short*)take((size_t)256 * 1024 * 2);
  unsigned short* wFH   = (unsigned short*)take((size_t)2304 * 1024 * 2);  // [w_f1T; w_h1T]
  unsigned short* w_f2T = (unsigned short*)take((size_t)1024 * 2048 * 2);
  unsigned short* w_s1T = (unsigned short*)take((size_t)64 * 2048 * 2);
  unsigned short* w_s2T = (unsigned short*)take((size_t)3072 * 64 * 2);
  unsigned short* ew1T  = (unsigned short*)take((size_t)NEXP * 64 * 2048 * 2);
  unsigned short* ew2T  = (unsigned short*)take((size_t)NEXP * 3072 * 64 * 2);
  if (off > ws_size) return;   // ~190 MB

  hipMemcpyAsync(out, x, TD4, hipMemcpyDeviceToDevice, stream);
  hipMemsetAsync(cnt, 0, 64, stream);

  dim3 tb(32, 8);
  transpose_cast<<<dim3(  8, 32, 1), tb, 0, stream>>>(w_r1, w_r1T, 1024,  256);
  transpose_cast<<<dim3( 64, 32, 1), tb, 0, stream>>>(w_f1, wFH, 1024, 2048);
  transpose_cast<<<dim3(  8, 32, 1), tb, 0, stream>>>(w_h1, wFH + (size_t)2048*1024, 1024, 256);
  transpose_cast<<<dim3( 32, 64, 1), tb, 0, stream>>>(w_f2, w_f2T, 2048, 1024);
  transpose_cast<<<dim3(  2, 64, 1), tb, 0, stream>>>(w_s1, w_s1T, 2048,   64);
  transpose_cast<<<dim3( 96,  2, 1), tb, 0, stream>>>(w_s2, w_s2T,   64, 3072);
  transpose_cast<<<dim3(  2, 64, 8), tb, 0, stream>>>(ew1,  ew1T,  2048,   64);
  transpose_cast<<<dim3( 96,  2, 8), tb, 0, stream>>>(ew2,  ew2T,    64, 3072);

  // ctx init (x-half = bf16(x), v-half = 0), then router
  ctx_k<<<2048, 256, 0, stream>>>(out, ctx);
  gemm_k<0><<<dim3(2, 128), 256, 0, stream>>>(
      ctx, 2048, w_r1T, b_r1, nullptr, 1024, 256, h1, nullptr,
      nullptr, nullptr, nullptr, nullptr);
  router_k<<<TOK / 4, 256, 0, stream>>>(h1, w_r2, b_r2, topi, topw);
  bucket_k<<<TOK * 2 / 256, 256, 0, stream>>>(topi, cnt, slots);
  desc_k<<<1, 64, 0, stream>>>(cnt, desc, ndsc);

  for (int it = 0; it < 2; it++) {
    exp1_k<<<NDBLK, 256, 0, stream>>>(ctx, desc, ndsc, slots,
                                      ew1T, eb1, w_s1T, b_s1, hiddenG);
    for (int h = 0; h < 2; h++) {
      exp2r_k<<<NDBLK, 256, 0, stream>>>(hiddenG, desc, ndsc, slots, topw,
                                         ew2T, eb2, swt, mu, ctx, padPK, h);
      exp2sc_k<<<TOK / 128, 256, 0, stream>>>(hiddenG, w_s2T, b_s2, swt, mu,
                                              ctx, padPK, xaccB, h);
    }
    // F1 + halt-gate hidden, fused (shared A = x_next)
    gemm_k<2><<<dim3(18, 128), 256, 0, stream>>>(
        xaccB, 1024, wFH, b_f1, b_h1, 1024, 2304, rh, h1,
        nullptr, nullptr, nullptr, nullptr);
    haltgate_k<<<TOK / 4, 256, 0, stream>>>(h1, w_h2, b_h2, halt);
    // F2: integ += halt*refined*iw; also writes bf16(integ) into ctx x-half
    gemm_k<1><<<dim3(8, 128), 256, 0, stream>>>(
        rh, 2048, w_f2T, b_f2, nullptr, 2048, 1024, nullptr, nullptr,
        halt, iw, out, ctx);
  }
}

// Round 5
// 1149.253 us; speedup vs baseline: 1.3548x; 1.3548x over previous
//
#include <hip/hip_runtime.h>

// FusedMoEIntegrator — MI355X/gfx950, round 4.
// Change vs round 3: expert phase regrouped by EXPERT-PAIR (28 pairs).
// Each pair-tile's tokens share {e0,e1,shared} weights, so exp2p computes all
// three paths per block and combines IN-REGISTER -> x_next/v_next written
// directly. Eliminates padPK (±128MB/iter), exp2sc (was 128-block
// latency-bound), combine, and all atomics. gemm/router path unchanged.

#define TOK   16384
#define DDIM  1024
#define NEXP  8
#define DTC   0.1f
#define NDESC 160   // >= 28 pairs + TOK/128 tiles

using f32x4 = __attribute__((ext_vector_type(4))) float;
using bfv8  = __attribute__((ext_vector_type(8))) short;

__device__ __forceinline__ unsigned short f2bf(float x){
  unsigned u = __builtin_bit_cast(unsigned, x);
  u += 0x7fffu + ((u >> 16) & 1u);
  return (unsigned short)(u >> 16);
}
__device__ __forceinline__ float bf2f(unsigned short h){
  return __builtin_bit_cast(float, ((unsigned)h) << 16);
}
__device__ __forceinline__ float geluf(float x){
  return 0.5f * x * (1.0f + erff(x * 0.7071067811865476f));
}
__device__ __forceinline__ float sigmf(float x){ return 1.0f/(1.0f+__expf(-x)); }
__device__ __forceinline__ float softpf(float x){
  return fmaxf(x, 0.0f) + __logf(1.0f + __expf(-fabsf(x)));
}
__device__ __forceinline__ f32x4 mfma16(bfv8 a, bfv8 b, f32x4 c){
  return __builtin_amdgcn_mfma_f32_16x16x32_bf16(a, b, c, 0, 0, 0);
}
typedef __attribute__((address_space(1))) const void gvoid_t;
typedef __attribute__((address_space(3))) void svoid_t;
__device__ __forceinline__ void gload16(const void* g, void* l){
  __builtin_amdgcn_global_load_lds((gvoid_t*)g, (svoid_t*)l, 16, 0, 0);
}

// -------- transpose+cast: src f32 [R][C] (batch z) -> dst bf16 [C][R] --------
__global__ __launch_bounds__(256) void transpose_cast(
    const float* __restrict__ src, unsigned short* __restrict__ dst, int R, int C)
{
  __shared__ float tile[32][33];
  size_t bo = (size_t)blockIdx.z * R * C;
  const float* s = src + bo;
  unsigned short* d = dst + bo;
  int c0 = blockIdx.x * 32, r0 = blockIdx.y * 32;
  int tx = threadIdx.x, ty = threadIdx.y;
  #pragma unroll
  for (int j = 0; j < 4; j++)
    tile[ty + 8*j][tx] = s[(size_t)(r0 + ty + 8*j) * C + c0 + tx];
  __syncthreads();
  #pragma unroll
  for (int j = 0; j < 4; j++)
    d[(size_t)(c0 + ty + 8*j) * R + r0 + tx] = f2bf(tile[tx][ty + 8*j]);
}

// -------- ctx init: x-half = bf16(out), v-half = 0 ---------------------------
__global__ __launch_bounds__(256) void ctx_k(
    const float* __restrict__ outf, unsigned short* __restrict__ ctx)
{
  const int n = TOK * 256;
  for (int i = blockIdx.x * 256 + threadIdx.x; i < n; i += gridDim.x * 256) {
    int t = i >> 8, c4 = (i & 255) * 4;
    float4 xi = ((const float4*)outf)[i];
    ushort4 xb = {f2bf(xi.x), f2bf(xi.y), f2bf(xi.z), f2bf(xi.w)};
    *(ushort4*)&ctx[(size_t)t*2048 + c4] = xb;
    *(ushort4*)&ctx[(size_t)t*2048 + 1024 + c4] = ushort4{0,0,0,0};
  }
}

// -------- main GEMM (unchanged from round 3) ---------------------------------
template<int EPI>
__global__ __launch_bounds__(256) void gemm_k(
    const unsigned short* __restrict__ A, int lda,
    const unsigned short* __restrict__ BT,
    const float* __restrict__ bias, const float* __restrict__ bias2,
    int Kd, int N,
    unsigned short* __restrict__ obf, unsigned short* __restrict__ obf2,
    const float* __restrict__ halt, const float* __restrict__ iw,
    float* __restrict__ integ, unsigned short* __restrict__ ctxX)
{
  __shared__ unsigned short As[128][64];
  __shared__ unsigned short Bs[128][64];
  const int total = gridDim.x * gridDim.y;
  const int bid = blockIdx.y * gridDim.x + blockIdx.x;
  const int swz = (bid & 7) * (total >> 3) + (bid >> 3);
  const int bx = swz % gridDim.x, by = swz / gridDim.x;

  const int tid  = threadIdx.x, lane = tid & 63, w = tid >> 6;
  const int wm   = w >> 1, wn = w & 1;
  const int gm0  = by * 128, gn0 = bx * 128;
  const int r8   = lane >> 3;
  const int sseg = (lane & 7) ^ r8;

  const unsigned short* aga[4];
  const unsigned short* bga[4];
  #pragma unroll
  for (int c = 0; c < 4; c++) {
    aga[c] = A  + (size_t)(gm0 + w*32 + c*8 + r8) * lda + sseg*8;
    bga[c] = BT + (size_t)(gn0 + w*32 + c*8 + r8) * Kd  + sseg*8;
  }

  f32x4 acc[4][4];
  #pragma unroll
  for (int i = 0; i < 4; i++)
    #pragma unroll
    for (int j = 0; j < 4; j++)
      acc[i][j] = f32x4{0.f,0.f,0.f,0.f};

  const int xr = (lane & 7) << 3;
  for (int k0 = 0; k0 < Kd; k0 += 64) {
    #pragma unroll
    for (int c = 0; c < 4; c++) gload16(aga[c] + k0, &As[w*32 + c*8][0]);
    #pragma unroll
    for (int c = 0; c < 4; c++) gload16(bga[c] + k0, &Bs[w*32 + c*8][0]);
    __syncthreads();
    #pragma unroll
    for (int kk = 0; kk < 64; kk += 32) {
      const int kof = kk + ((lane >> 4) << 3);
      bfv8 a[4], b[4];
      #pragma unroll
      for (int mf = 0; mf < 4; mf++)
        a[mf] = *(const bfv8*)&As[wm*64 + mf*16 + (lane & 15)][kof ^ xr];
      #pragma unroll
      for (int nf = 0; nf < 4; nf++)
        b[nf] = *(const bfv8*)&Bs[wn*64 + nf*16 + (lane & 15)][kof ^ xr];
      #pragma unroll
      for (int mf = 0; mf < 4; mf++)
        #pragma unroll
        for (int nf = 0; nf < 4; nf++)
          acc[mf][nf] = mfma16(a[mf], b[nf], acc[mf][nf]);
    }
    __syncthreads();
  }

  #pragma unroll
  for (int mf = 0; mf < 4; mf++) {
    #pragma unroll
    for (int nf = 0; nf < 4; nf++) {
      int col = gn0 + wn*64 + nf*16 + (lane & 15);
      float bc;
      if (EPI == 2) bc = (col < 2048) ? bias[col] : bias2[col - 2048];
      else          bc = bias[col];
      #pragma unroll
      for (int r = 0; r < 4; r++) {
        int row = gm0 + wm*64 + mf*16 + ((lane >> 4) << 2) + r;
        float v = acc[mf][nf][r] + bc;
        if (EPI == 0) {
          obf[(size_t)row * N + col] = f2bf(geluf(v));
        } else if (EPI == 2) {
          if (col < 2048) obf [(size_t)row * 2048 + col]        = f2bf(geluf(v));
          else            obf2[(size_t)row * 256 + (col - 2048)] = f2bf(geluf(v));
        } else {
          size_t ix = (size_t)row * DDIM + col;
          float nv = integ[ix] + halt[row] * v * iw[col];
          integ[ix] = nv;
          ctxX[(size_t)row * 2048 + col] = f2bf(nv);
        }
      }
    }
  }
}

// -------- router second stage ------------------------------------------------
__global__ __launch_bounds__(256) void router_k(
    const unsigned short* __restrict__ h1, const float* __restrict__ w_r2,
    const float* __restrict__ b_r2, int* __restrict__ topi, float* __restrict__ topw)
{
  int t = blockIdx.x * 4 + (threadIdx.x >> 6);
  int lane = threadIdx.x & 63;
  const unsigned short* hp = h1 + (size_t)t * 256 + lane * 4;
  float hv[4];
  #pragma unroll
  for (int j = 0; j < 4; j++) hv[j] = bf2f(hp[j]);
  float acc[8];
  #pragma unroll
  for (int e = 0; e < 8; e++) acc[e] = 0.f;
  #pragma unroll
  for (int j = 0; j < 4; j++) {
    const float* wr = w_r2 + (size_t)(lane*4 + j) * 8;
    #pragma unroll
    for (int e = 0; e < 8; e++) acc[e] += hv[j] * wr[e];
  }
  #pragma unroll
  for (int off = 32; off > 0; off >>= 1)
    #pragma unroll
    for (int e = 0; e < 8; e++) acc[e] += __shfl_xor(acc[e], off);
  if (lane == 0) {
    float lg[8];
    #pragma unroll
    for (int e = 0; e < 8; e++) lg[e] = acc[e] + b_r2[e];
    int i0 = 0; float m0 = lg[0];
    #pragma unroll
    for (int e = 1; e < 8; e++) if (lg[e] > m0) { m0 = lg[e]; i0 = e; }
    int i1 = -1; float m1 = -3.4e38f;
    #pragma unroll
    for (int e = 0; e < 8; e++) if (e != i0 && lg[e] > m1) { m1 = lg[e]; i1 = e; }
    float w0 = 1.0f / (1.0f + expf(m1 - m0));
    topi[t*2] = i0; topi[t*2+1] = i1;
    topw[t*2] = w0; topw[t*2+1] = 1.0f - w0;
  }
}

// -------- halt gate second stage ---------------------------------------------
__global__ __launch_bounds__(256) void haltgate_k(
    const unsigned short* __restrict__ h1, const float* __restrict__ w_h2,
    const float* __restrict__ b_h2, float* __restrict__ halt)
{
  int t = blockIdx.x * 4 + (threadIdx.x >> 6);
  int lane = threadIdx.x & 63;
  const unsigned short* hp = h1 + (size_t)t * 256 + lane * 4;
  float s = 0.f;
  #pragma unroll
  for (int j = 0; j < 4; j++) s += bf2f(hp[j]) * w_h2[lane*4 + j];
  #pragma unroll
  for (int off = 32; off > 0; off >>= 1) s += __shfl_xor(s, off);
  if (lane == 0) halt[t] = sigmf(s + b_h2[0]);
}

// -------- pair bucketing: group tokens by canonical expert pair --------------
__global__ __launch_bounds__(256) void pairb_k(
    const int* __restrict__ topi, const float* __restrict__ topw,
    int* __restrict__ cnt, int* __restrict__ plist, float* __restrict__ wA)
{
  int t = blockIdx.x * 256 + threadIdx.x;
  int a = topi[2*t], b = topi[2*t+1];
  float wa = topw[2*t];
  if (a > b) { int tmp = a; a = b; b = tmp; wa = 1.0f - wa; }
  int pid = a * 8 + b;
  int pos = atomicAdd(&cnt[pid], 1);
  plist[pid * TOK + pos] = t;
  wA[t] = wa;    // weight of the LOWER-indexed expert
}

// desc entry: {pid, goff, cnt, hbase}; 128-token tiles, 384 hidden rows each.
__global__ void desc_k(const int* __restrict__ cnt, int4* __restrict__ desc,
                       int* __restrict__ ndesc)
{
  if (threadIdx.x == 0 && blockIdx.x == 0) {
    int nt = 0, hb = 0;
    for (int p = 0; p < 64; p++) {
      int c = cnt[p];
      for (int o = 0; o < c; o += 128) {
        int rem = c - o; if (rem > 128) rem = 128;
        desc[nt] = make_int4(p, o, rem, hb);
        nt++; hb += 384;
      }
    }
    ndesc[0] = nt;
  }
}

// -------- exp1p: hidden = gelu(ctx @ w1[path] + b1), path = blockIdx.y -------
// path 0 = low expert of pair, 1 = high expert, 2 = shared.
__global__ __launch_bounds__(256) void exp1p_k(
    const unsigned short* __restrict__ ctx,
    const int4* __restrict__ desc, const int* __restrict__ ndesc,
    const int* __restrict__ plist,
    const unsigned short* __restrict__ ew1T, const float* __restrict__ eb1,
    const unsigned short* __restrict__ ws1T, const float* __restrict__ bs1,
    unsigned short* __restrict__ hiddenG)
{
  __shared__ unsigned short As[128][64];
  __shared__ unsigned short Bs[64][64];
  __shared__ int s_tok[128];
  if (blockIdx.x >= ndesc[0]) return;
  int4 dd = desc[blockIdx.x];
  const int pid = dd.x, goff = dd.y, cnt = dd.z, hbase = dd.w;
  const int path = blockIdx.y;
  const int ep = (path == 0) ? (pid >> 3) : (pid & 7);
  const unsigned short* w1 = (path < 2) ? ew1T + (size_t)ep * 64 * 2048 : ws1T;
  const float* b1 = (path < 2) ? eb1 + ep * 64 : bs1;
  const int tid = threadIdx.x, lane = tid & 63, w = tid >> 6;

  if (tid < 128)
    s_tok[tid] = (tid < cnt) ? plist[pid * TOK + goff + tid] : 0;
  __syncthreads();

  const int arow = w*8 + (lane >> 3);
  const int sseg = (lane & 7) ^ (lane >> 3);
  const unsigned short* asrc[4];
  #pragma unroll
  for (int q = 0; q < 4; q++)
    asrc[q] = ctx + (size_t)s_tok[q*32 + arow] * 2048 + sseg * 8;
  const unsigned short* bsrc[2];
  #pragma unroll
  for (int q = 0; q < 2; q++)
    bsrc[q] = w1 + (size_t)(q*32 + arow) * 2048 + sseg * 8;

  f32x4 acc[2][4];
  #pragma unroll
  for (int i = 0; i < 2; i++)
    #pragma unroll
    for (int j = 0; j < 4; j++)
      acc[i][j] = f32x4{0.f,0.f,0.f,0.f};

  const int xr = (lane & 7) << 3;
  for (int k0 = 0; k0 < 2048; k0 += 64) {
    #pragma unroll
    for (int q = 0; q < 4; q++) gload16(asrc[q] + k0, &As[q*32 + w*8][0]);
    #pragma unroll
    for (int q = 0; q < 2; q++) gload16(bsrc[q] + k0, &Bs[q*32 + w*8][0]);
    __syncthreads();
    #pragma unroll
    for (int kk = 0; kk < 64; kk += 32) {
      const int kof = kk + ((lane >> 4) << 3);
      bfv8 a[2], b[4];
      #pragma unroll
      for (int mf = 0; mf < 2; mf++)
        a[mf] = *(const bfv8*)&As[w*32 + mf*16 + (lane & 15)][kof ^ xr];
      #pragma unroll
      for (int nf = 0; nf < 4; nf++)
        b[nf] = *(const bfv8*)&Bs[nf*16 + (lane & 15)][kof ^ xr];
      #pragma unroll
      for (int mf = 0; mf < 2; mf++)
        #pragma unroll
        for (int nf = 0; nf < 4; nf++)
          acc[mf][nf] = mfma16(a[mf], b[nf], acc[mf][nf]);
    }
    __syncthreads();
  }

  #pragma unroll
  for (int mf = 0; mf < 2; mf++) {
    #pragma unroll
    for (int nf = 0; nf < 4; nf++) {
      int col = nf*16 + (lane & 15);
      float bb = b1[col];
      #pragma unroll
      for (int r = 0; r < 4; r++) {
        int row = w*32 + mf*16 + ((lane >> 4) << 2) + r;
        hiddenG[(size_t)(hbase + path*128 + row) * 64 + col] =
            f2bf(geluf(acc[mf][nf][r] + bb));
      }
    }
  }
}

// -------- exp2p: 3-path phase-2 GEMM + in-register combine -------------------
// grid (NDESC, 2, 4): y = 64-row half of the tile, z = 256-d quarter.
__global__ __launch_bounds__(256) void exp2p_k(
    const unsigned short* __restrict__ hiddenG,
    const int4* __restrict__ desc, const int* __restrict__ ndesc,
    const int* __restrict__ plist, const float* __restrict__ wA,
    const unsigned short* __restrict__ ew2T, const float* __restrict__ eb2,
    const unsigned short* __restrict__ ws2T, const float* __restrict__ bs2,
    const float* __restrict__ swp, const float* __restrict__ mu,
    unsigned short* __restrict__ ctx, unsigned short* __restrict__ xaccB)
{
  __shared__ unsigned short Hs[192][64];
  __shared__ unsigned short W2s[192][64];
  __shared__ int   s_tok[64];
  __shared__ float s_w[64];
  if (blockIdx.x >= ndesc[0]) return;
  int4 dd = desc[blockIdx.x];
  const int pid = dd.x, goff = dd.y, cnt = dd.z, hbase = dd.w;
  const int rhf = blockIdx.y;
  const int cnth = cnt - rhf * 64;
  if (cnth <= 0) return;
  const int e0 = pid >> 3, e1 = pid & 7;
  const int tid = threadIdx.x, lane = tid & 63, w = tid >> 6;
  const float sw = sigmf(swp[0]);

  if (tid < 64) {
    int gr = rhf*64 + tid;
    int tok = 0; float wa = 0.f;
    if (gr < cnt) { tok = plist[pid * TOK + goff + gr]; wa = wA[tok]; }
    s_tok[tid] = tok; s_w[tid] = wa;
  }
  const int srow = w*8 + (lane >> 3);
  const int sseg = (lane & 7) ^ (lane >> 3);
  #pragma unroll
  for (int q = 0; q < 6; q++) {
    int row = q*32 + srow;                      // 0..191 = 3 paths x 64 rows
    gload16(hiddenG + (size_t)(hbase + (row >> 6)*128 + rhf*64 + (row & 63))*64 + sseg*8,
            &Hs[q*32 + w*8][0]);
  }
  __syncthreads();

  const int xr = (lane & 7) << 3;
  const unsigned short* w2b[3] = { ew2T + (size_t)e0*3072*64,
                                   ew2T + (size_t)e1*3072*64, ws2T };
  const float* b2b[3] = { eb2 + e0*3072, eb2 + e1*3072, bs2 };

  for (int dcq = 0; dcq < 4; dcq++) {
    const int d00 = blockIdx.z * 256 + dcq * 64;
    // x, v for my (rows x cols) once per chunk
    float xx[4][4], vv[4][4], vtot[4][4], gvtot[4][4];
    int   toks[4]; float cwa[4];
    #pragma unroll
    for (int r = 0; r < 4; r++) {
      int row = w*16 + ((lane >> 4) << 2) + r;
      toks[r] = s_tok[row]; cwa[r] = s_w[row];
      #pragma unroll
      for (int cf = 0; cf < 4; cf++) {
        int d = d00 + cf*16 + (lane & 15);
        xx[cf][r] = bf2f(ctx[(size_t)toks[r]*2048 + d]);
        vv[cf][r] = bf2f(ctx[(size_t)toks[r]*2048 + 1024 + d]);
        vtot[cf][r] = 0.f; gvtot[cf][r] = 0.f;
      }
    }
    #pragma unroll
    for (int path = 0; path < 3; path++) {
      #pragma unroll
      for (int q = 0; q < 6; q++) {
        int row  = q*32 + srow;
        int grow = (row >> 6)*1024 + d00 + (row & 63);
        gload16(w2b[path] + (size_t)grow*64 + sseg*8, &W2s[q*32 + w*8][0]);
      }
      __syncthreads();
      bfv8 a[2];
      #pragma unroll
      for (int kk = 0; kk < 2; kk++)
        a[kk] = *(const bfv8*)&Hs[path*64 + w*16 + (lane & 15)]
                               [(kk*32 + ((lane >> 4) << 3)) ^ xr];
      f32x4 acc[12];
      #pragma unroll
      for (int j = 0; j < 12; j++) acc[j] = f32x4{0.f,0.f,0.f,0.f};
      #pragma unroll
      for (int kk = 0; kk < 2; kk++) {
        const int kof = kk*32 + ((lane >> 4) << 3);
        #pragma unroll
        for (int nf = 0; nf < 12; nf++) {
          bfv8 b = *(const bfv8*)&W2s[nf*16 + (lane & 15)][kof ^ xr];
          acc[nf] = mfma16(a[kk], b, acc[nf]);
        }
      }
      const float* b2 = b2b[path];
      #pragma unroll
      for (int cf = 0; cf < 4; cf++) {
        int d = d00 + cf*16 + (lane & 15);
        float ba = b2[d], bb = b2[1024 + d], bg = b2[2048 + d];
        float muv = mu[d];
        #pragma unroll
        for (int r = 0; r < 4; r++) {
          float cw = (path == 0) ? (1.f - sw) * cwa[r]
                   : (path == 1) ? (1.f - sw) * (1.f - cwa[r]) : sw;
          float al = sigmf(acc[cf][r] + ba);
          float be = softpf(acc[4 + cf][r] + bb);
          float ga = sigmf(acc[8 + cf][r] + bg);
          float vn = al * vv[cf][r] - be * (xx[cf][r] - muv);
          vtot[cf][r]  += cw * vn;
          gvtot[cf][r] += cw * ga * vn;
        }
      }
      __syncthreads();
    }
    // write x_next / v_next
    #pragma unroll
    for (int r = 0; r < 4; r++) {
      int row = w*16 + ((lane >> 4) << 2) + r;
      if (row >= cnth) continue;
      int tok = toks[r];
      #pragma unroll
      for (int cf = 0; cf < 4; cf++) {
        int d = d00 + cf*16 + (lane & 15);
        xaccB[(size_t)tok*1024 + d]        = f2bf(xx[cf][r] + DTC * gvtot[cf][r]);
        ctx[(size_t)tok*2048 + 1024 + d]   = f2bf(vtot[cf][r]);
      }
    }
  }
}

// -----------------------------------------------------------------------------
extern "C" void kernel_launch(void* const* d_in, const int* in_sizes, int n_in,
                              void* d_out, int out_size, void* d_ws, size_t ws_size,
                              hipStream_t stream)
{
  const float* x    = (const float*)d_in[0];
  const float* w_r1 = (const float*)d_in[1];
  const float* b_r1 = (const float*)d_in[2];
  const float* w_r2 = (const float*)d_in[3];
  const float* b_r2 = (const float*)d_in[4];
  const float* w_h1 = (const float*)d_in[5];
  const float* b_h1 = (const float*)d_in[6];
  const float* w_h2 = (const float*)d_in[7];
  const float* b_h2 = (const float*)d_in[8];
  const float* ew1  = (const float*)d_in[9];
  const float* eb1  = (const float*)d_in[10];
  const float* ew2  = (const float*)d_in[11];
  const float* eb2  = (const float*)d_in[12];
  const float* w_s1 = (const float*)d_in[13];
  const float* b_s1 = (const float*)d_in[14];
  const float* w_s2 = (const float*)d_in[15];
  const float* b_s2 = (const float*)d_in[16];
  const float* swt  = (const float*)d_in[17];
  const float* w_f1 = (const float*)d_in[18];
  const float* b_f1 = (const float*)d_in[19];
  const float* w_f2 = (const float*)d_in[20];
  const float* b_f2 = (const float*)d_in[21];
  const float* iw   = (const float*)d_in[22];
  const float* mu   = (const float*)d_in[23];
  float* out = (float*)d_out;        // doubles as `integrated`

  char* ws = (char*)d_ws;
  size_t off = 0;
  auto take = [&](size_t bytes) -> char* {
    char* p = ws + off;
    off = (off + bytes + 255) & ~(size_t)255;
    return p;
  };
  const size_t TD4 = (size_t)TOK * DDIM * 4;
  unsigned short* xaccB = (unsigned short*)take((size_t)TOK * 1024 * 2);
  unsigned short* ctx   = (unsigned short*)take((size_t)TOK * 2048 * 2);
  unsigned short* rh    = (unsigned short*)take((size_t)TOK * 2048 * 2);
  unsigned short* hiddenG = (unsigned short*)take((size_t)NDESC * 384 * 64 * 2);
  unsigned short* h1 = (unsigned short*)take((size_t)TOK * 256 * 2);
  float* halt = (float*)take((size_t)TOK * 4);
  int*   topi = (int*)take((size_t)TOK * 2 * 4);
  float* topw = (float*)take((size_t)TOK * 2 * 4);
  int*   cnt  = (int*)take(64 * 4);
  int*   ndsc = (int*)take(64);
  int4*  desc = (int4*)take((size_t)NDESC * 16);
  int*   plist= (int*)take((size_t)64 * TOK * 4);
  float* wAa  = (float*)take((size_t)TOK * 4);
  unsigned short* w_r1T = (unsigned short*)take((size_t)256 * 1024 * 2);
  unsigned short* wFH   = (unsigned short*)take((size_t)2304 * 1024 * 2);
  unsigned short* w_f2T = (unsigned short*)take((size_t)1024 * 2048 * 2);
  unsigned short* w_s1T = (unsigned short*)take((size_t)64 * 2048 * 2);
  unsigned short* w_s2T = (unsigned short*)take((size_t)3072 * 64 * 2);
  unsigned short* ew1T  = (unsigned short*)take((size_t)NEXP * 64 * 2048 * 2);
  unsigned short* ew2T  = (unsigned short*)take((size_t)NEXP * 3072 * 64 * 2);
  if (off > ws_size) return;   // ~200 MB

  hipMemcpyAsync(out, x, TD4, hipMemcpyDeviceToDevice, stream);
  hipMemsetAsync(cnt, 0, 64 * 4, stream);

  dim3 tb(32, 8);
  transpose_cast<<<dim3(  8, 32, 1), tb, 0, stream>>>(w_r1, w_r1T, 1024,  256);
  transpose_cast<<<dim3( 64, 32, 1), tb, 0, stream>>>(w_f1, wFH, 1024, 2048);
  transpose_cast<<<dim3(  8, 32, 1), tb, 0, stream>>>(w_h1, wFH + (size_t)2048*1024, 1024, 256);
  transpose_cast<<<dim3( 32, 64, 1), tb, 0, stream>>>(w_f2, w_f2T, 2048, 1024);
  transpose_cast<<<dim3(  2, 64, 1), tb, 0, stream>>>(w_s1, w_s1T, 2048,   64);
  transpose_cast<<<dim3( 96,  2, 1), tb, 0, stream>>>(w_s2, w_s2T,   64, 3072);
  transpose_cast<<<dim3(  2, 64, 8), tb, 0, stream>>>(ew1,  ew1T,  2048,   64);
  transpose_cast<<<dim3( 96,  2, 8), tb, 0, stream>>>(ew2,  ew2T,    64, 3072);

  // ctx init, router, pair bucketing
  ctx_k<<<2048, 256, 0, stream>>>(out, ctx);
  gemm_k<0><<<dim3(2, 128), 256, 0, stream>>>(
      ctx, 2048, w_r1T, b_r1, nullptr, 1024, 256, h1, nullptr,
      nullptr, nullptr, nullptr, nullptr);
  router_k<<<TOK / 4, 256, 0, stream>>>(h1, w_r2, b_r2, topi, topw);
  pairb_k<<<TOK / 256, 256, 0, stream>>>(topi, topw, cnt, plist, wAa);
  desc_k<<<1, 64, 0, stream>>>(cnt, desc, ndsc);

  for (int it = 0; it < 2; it++) {
    exp1p_k<<<dim3(NDESC, 3), 256, 0, stream>>>(
        ctx, desc, ndsc, plist, ew1T, eb1, w_s1T, b_s1, hiddenG);
    exp2p_k<<<dim3(NDESC, 2, 4), 256, 0, stream>>>(
        hiddenG, desc, ndsc, plist, wAa, ew2T, eb2, w_s2T, b_s2,
        swt, mu, ctx, xaccB);
    // F1 + halt hidden fused
    gemm_k<2><<<dim3(18, 128), 256, 0, stream>>>(
        xaccB, 1024, wFH, b_f1, b_h1, 1024, 2304, rh, h1,
        nullptr, nullptr, nullptr, nullptr);
    haltgate_k<<<TOK / 4, 256, 0, stream>>>(h1, w_h2, b_h2, halt);
    // F2: integ += halt*refined*iw; writes bf16(integ) into ctx x-half
    gemm_k<1><<<dim3(8, 128), 256, 0, stream>>>(
        rh, 2048, w_f2T, b_f2, nullptr, 2048, 1024, nullptr, nullptr,
        halt, iw, out, ctx);
  }
}